// Round 8
// baseline (197.242 us; speedup 1.0000x reference)
//
#include <hip/hip_runtime.h>
#include <hip/hip_bf16.h>
#include <hip/hip_fp16.h>

#define D 64
#define KPER 20

typedef __attribute__((ext_vector_type(8))) short short8;
typedef __attribute__((ext_vector_type(4))) float floatx4;

__device__ __forceinline__ unsigned short f2bfu(float x) {
    __hip_bfloat16 h = __float2bfloat16(x);
    return *reinterpret_cast<unsigned short*>(&h);
}
// f16 bits (tables are f16: 3 more mantissa bits than bf16 AND enables v_pk_* math)
__device__ __forceinline__ unsigned short f2hu(float x) {
    __half h = __float2half(x);
    return *reinterpret_cast<unsigned short*>(&h);
}
union UH2 { unsigned u; __half2 h; };
__device__ __forceinline__ __half2 u2h2(unsigned u) { UH2 x; x.u = u; return x.h; }
__device__ __forceinline__ unsigned pick4(uint4 v, int p) {
    return p == 0 ? v.x : p == 1 ? v.y : p == 2 ? v.z : v.w;   // p is compile-time under unroll
}

// HW packed f32->bf16 convert (RNE): src0 -> bits[15:0], src1 -> bits[31:16]
__device__ __forceinline__ unsigned cvt2bf(float lo, float hi) {
    unsigned r;
    asm("v_cvt_pk_bf16_f32 %0, %1, %2" : "=v"(r) : "v"(lo), "v"(hi));
    return r;
}

// guaranteed-available packed f16 max (avoid header-version-dependent __hmax2)
__device__ __forceinline__ __half2 pk_max(__half2 a, __half2 b) {
    __half2 r;
    asm("v_pk_max_f16 %0, %1, %2" : "=v"(r) : "v"(a), "v"(b));
    return r;
}

__device__ __forceinline__ float fast_tanh(float x) {
    float xc = fminf(fmaxf(x, -15.f), 15.f);
    float e = __expf(2.f * xc);
    return 1.f - 2.f * __builtin_amdgcn_rcpf(1.f + e);
}

// ---- DPP reductions (VALU pipe) ----------------------------------------
template<int CTRL>
__device__ __forceinline__ float dpp_add(float x) {
    int t = __builtin_amdgcn_update_dpp(0, __float_as_int(x), CTRL, 0xf, 0xf, true);
    return x + __int_as_float(t);
}
template<int CTRL>
__device__ __forceinline__ float dpp_max(float x) {
    int xi = __float_as_int(x);
    int t = __builtin_amdgcn_update_dpp(xi, xi, CTRL, 0xf, 0xf, false);
    return fmaxf(x, __int_as_float(t));
}
__device__ __forceinline__ float wave_sum_b(float x) {
    x = dpp_add<0x111>(x); x = dpp_add<0x112>(x);
    x = dpp_add<0x114>(x); x = dpp_add<0x118>(x);
    x = dpp_add<0x142>(x); x = dpp_add<0x143>(x);
    return __int_as_float(__builtin_amdgcn_readlane(__float_as_int(x), 63));
}
__device__ __forceinline__ float wave_max_b(float x) {
    x = dpp_max<0x111>(x); x = dpp_max<0x112>(x);
    x = dpp_max<0x114>(x); x = dpp_max<0x118>(x);
    x = dpp_max<0x142>(x); x = dpp_max<0x143>(x);
    return __int_as_float(__builtin_amdgcn_readlane(__float_as_int(x), 63));
}
// sum over each 8-lane subgroup; results at lanes 7/15 of each DPP row.
__device__ __forceinline__ float row8_sum(float x) {
    x = dpp_add<0x111>(x); x = dpp_add<0x112>(x);
    x = dpp_add<0x114>(x);
    return x;
}

// ---- prep: repack W into fragment-major bf16, convert rel/ws/fb to f16,
// zero out. (R7 lesson: direct f32 W-frag reads in proj cost ~3-4 us —
// the packed-Wup coalesced path is faster; keep the separate prep.) -----
__global__ __launch_bounds__(256) void prep(
        const float* __restrict__ Wc, const float* __restrict__ Wu,
        const float* __restrict__ relf, const float* __restrict__ wsf,
        const float* __restrict__ fbf,
        unsigned short* __restrict__ Wcp, unsigned short* __restrict__ Wup,
        unsigned short* __restrict__ relb, unsigned short* __restrict__ wsh,
        unsigned short* __restrict__ fbh, float* __restrict__ outz,
        int nout, int nrel) {
    int tid = blockIdx.x * 256 + threadIdx.x;
    int nth = gridDim.x * 256;
    for (int i = tid; i < 4 * 2 * 64 * 8; i += nth) {
        int j = i & 7, lane = (i >> 3) & 63, f = i >> 9;
        int ct = f >> 1, kt = f & 1;
        int m = lane & 15, quad = lane >> 4;
        Wcp[i] = f2bfu(Wc[(kt * 32 + quad * 8 + j) * 64 + ct * 16 + m]);
    }
    for (int i = tid; i < 4 * 8 * 64 * 8; i += nth) {
        int j = i & 7, lane = (i >> 3) & 63, f = i >> 9;
        int ct = f >> 3, kt = f & 7;
        int m = lane & 15, quad = lane >> 4;
        Wup[i] = f2bfu(Wu[(kt * 32 + quad * 8 + j) * 64 + ct * 16 + m]);
    }
    for (int i = tid; i < nrel; i += nth) relb[i] = f2hu(relf[i]);
    for (int i = tid; i < 8 * D; i += nth) wsh[i] = f2hu(wsf[i]);
    for (int i = tid; i < D; i += nth) fbh[i] = f2hu(fbf[i]);
    for (int i = tid; i < nout; i += nth) outz[i] = 0.0f;
}

// ---- K=64 projection, pair of row-tiles per wave; packed-W frag init ---
__device__ __forceinline__ void proj64_pair(const float* __restrict__ h,
        const unsigned short* __restrict__ Wp, const float* __restrict__ b,
        unsigned short* __restrict__ out, int rt0) {
    constexpr int K = 64, KT = 2, CTN = 4;
    int lane = threadIdx.x & 63;
    int m = lane & 15, quad = lane >> 4;
    short8 bfr[CTN][KT];
    #pragma unroll
    for (int ct = 0; ct < CTN; ++ct)
        #pragma unroll
        for (int kt = 0; kt < KT; ++kt)
            bfr[ct][kt] = *(const short8*)(Wp + (((ct * 2 + kt) * 64 + lane) << 3));
    float bv[CTN];
    #pragma unroll
    for (int ct = 0; ct < CTN; ++ct) bv[ct] = b[ct * 16 + m];
    int rt1 = rt0 + 1;
    const float* hrow0 = h + (size_t)(rt0 * 16 + m) * K + quad * 8;
    const float* hrow1 = h + (size_t)(rt1 * 16 + m) * K + quad * 8;
    floatx4 a0[KT][2], a1[KT][2];
    #pragma unroll
    for (int kt = 0; kt < KT; ++kt) {
        a0[kt][0] = *(const floatx4*)(hrow0 + kt * 32);
        a0[kt][1] = *(const floatx4*)(hrow0 + kt * 32 + 4);
        a1[kt][0] = *(const floatx4*)(hrow1 + kt * 32);
        a1[kt][1] = *(const floatx4*)(hrow1 + kt * 32 + 4);
    }
    #pragma unroll
    for (int t = 0; t < 2; ++t) {
        floatx4 (*ar)[2] = t ? a1 : a0;
        int rt = t ? rt1 : rt0;
        floatx4 acc[CTN];
        #pragma unroll
        for (int ct = 0; ct < CTN; ++ct) acc[ct] = floatx4{0.f, 0.f, 0.f, 0.f};
        #pragma unroll
        for (int kt = 0; kt < KT; ++kt) {
            union { uint4 u; short8 s; } cc;
            cc.u.x = cvt2bf(ar[kt][0][0], ar[kt][0][1]);
            cc.u.y = cvt2bf(ar[kt][0][2], ar[kt][0][3]);
            cc.u.z = cvt2bf(ar[kt][1][0], ar[kt][1][1]);
            cc.u.w = cvt2bf(ar[kt][1][2], ar[kt][1][3]);
            short8 af = cc.s;
            #pragma unroll
            for (int ct = 0; ct < CTN; ++ct)
                acc[ct] = __builtin_amdgcn_mfma_f32_16x16x32_bf16(af, bfr[ct][kt], acc[ct], 0, 0, 0);
        }
        #pragma unroll
        for (int ct = 0; ct < CTN; ++ct) {
            int col = ct * 16 + m;
            #pragma unroll
            for (int reg = 0; reg < 4; ++reg) {
                int row = rt * 16 + quad * 4 + reg;
                out[(size_t)row * 64 + col] = f2hu(fast_tanh(acc[ct][reg] + bv[ct]));
            }
        }
    }
}

// ---- K=256 projection: ONE (rt, ct-half) task per wave. R7 showed proj
// is latency-bound (MfmaUtil 2%, VALUBusy 11%, HBM 19%) with ~2 serial
// tiles/wave; halving per-wave work and doubling wave count (3200->6250)
// applies the TLP fix that worked for edge in R6. ------------------------
__device__ __forceinline__ void proj256_one(const float* __restrict__ h,
        const unsigned short* __restrict__ Wp, const float* __restrict__ b,
        unsigned short* __restrict__ out, int ct0, int rt) {
    constexpr int K = 256, KT = 8, CTN = 2;
    int lane = threadIdx.x & 63;
    int m = lane & 15, quad = lane >> 4;
    short8 bfr[CTN][KT];
    #pragma unroll
    for (int ct = 0; ct < CTN; ++ct)
        #pragma unroll
        for (int kt = 0; kt < KT; ++kt)
            bfr[ct][kt] = *(const short8*)(Wp + ((((ct0 + ct) * 8 + kt) * 64 + lane) << 3));
    float bv[CTN];
    #pragma unroll
    for (int ct = 0; ct < CTN; ++ct) bv[ct] = b[(ct0 + ct) * 16 + m];
    floatx4 acc[CTN];
    #pragma unroll
    for (int ct = 0; ct < CTN; ++ct) acc[ct] = floatx4{0.f, 0.f, 0.f, 0.f};
    const float* hrow = h + (size_t)(rt * 16 + m) * K + quad * 8;
    #pragma unroll
    for (int kt = 0; kt < KT; ++kt) {
        floatx4 v0 = *(const floatx4*)(hrow + kt * 32);
        floatx4 v1 = *(const floatx4*)(hrow + kt * 32 + 4);
        union { uint4 u; short8 s; } cc;
        cc.u.x = cvt2bf(v0[0], v0[1]);
        cc.u.y = cvt2bf(v0[2], v0[3]);
        cc.u.z = cvt2bf(v1[0], v1[1]);
        cc.u.w = cvt2bf(v1[2], v1[3]);
        short8 af = cc.s;
        #pragma unroll
        for (int ct = 0; ct < CTN; ++ct)
            acc[ct] = __builtin_amdgcn_mfma_f32_16x16x32_bf16(af, bfr[ct][kt], acc[ct], 0, 0, 0);
    }
    #pragma unroll
    for (int ct = 0; ct < CTN; ++ct) {
        int col = (ct0 + ct) * 16 + m;
        #pragma unroll
        for (int reg = 0; reg < 4; ++reg) {
            int row = rt * 16 + quad * 4 + reg;
            out[(size_t)row * 64 + col] = f2hu(fast_tanh(acc[ct][reg] + bv[ct]));
        }
    }
}

// Fused proj: proj256 single-task waves FIRST (bulk of work), then proj64.
// Adjacent waves (task 2k, 2k+1) share the same h row-tile -> L1 reuse.
__global__ __launch_bounds__(256) void proj_fused(
        const float* __restrict__ hcon, const unsigned short* __restrict__ Wcp,
        const float* __restrict__ bc,
        const float* __restrict__ hun, const unsigned short* __restrict__ Wup,
        const float* __restrict__ bu,
        unsigned short* __restrict__ hc, unsigned short* __restrict__ hu,
        int t256, int g256b) {
    int bid = blockIdx.x;
    int w = threadIdx.x >> 6;
    if (bid < g256b) {
        int task = bid * 4 + w;
        if (task < 2 * t256)
            proj256_one(hun, Wup, bu, hu, (task & 1) * 2, task >> 1);
    } else {
        int wid = (bid - g256b) * 4 + w;
        proj64_pair(hcon, Wcp, bc, hc, wid * 2);
    }
}

// Packed-f16 F-layer for ONE edge; each lane owns 8 features (4 __half2),
// gathered as ONE dwordx4 per feature table (8 lanes x 16B = full 128B row).
__device__ __forceinline__ float edge_acc8(
        uint4 G0, uint4 G2, uint4 G3, uint4 G4, uint4 F1,
        const uint4* __restrict__ wk4, uint4 fb4,
        floatx4 ow0, floatx4 ow1, __half2 z2) {
    float acc = 0.f;
    #pragma unroll
    for (int p = 0; p < 4; ++p) {
        __half2 F0 = u2h2(pick4(G0, p));
        __half2 F2 = u2h2(pick4(G2, p));
        __half2 F3 = u2h2(pick4(G3, p));
        __half2 F4 = u2h2(pick4(G4, p));
        __half2 f1 = u2h2(pick4(F1, p));
        __half2 fb2 = u2h2(pick4(fb4, p));
        __half2 w0 = u2h2(pick4(wk4[0], p));
        __half2 w1 = u2h2(pick4(wk4[1], p));
        __half2 w2 = u2h2(pick4(wk4[2], p));
        __half2 w3 = u2h2(pick4(wk4[3], p));
        __half2 w4 = u2h2(pick4(wk4[4], p));
        __half2 w5 = u2h2(pick4(wk4[5], p));
        __half2 w6 = u2h2(pick4(wk4[6], p));
        __half2 w7 = u2h2(pick4(wk4[7], p));
        __half2 t1 = __hfma2(F2, w1, w0);
        __half2 t2 = __hfma2(F2, w5, w4);
        __half2 t3 = __hfma2(F2, w3, w2);
        __half2 t4 = __hfma2(F2, w7, w6);
        __half2 uu = __hfma2(F0, t1, __hmul2(f1, t2));
        __half2 vv = __hfma2(F0, t3, __hmul2(f1, t4));
        __half2 od = __hfma2(F3, uu, __hfma2(F4, vv, fb2));
        __half2 r  = pk_max(od, z2);
        float2 rf  = __half22float2(r);
        float owa = (p < 2) ? ow0[2 * p]     : ow1[2 * p - 4];
        float owb = (p < 2) ? ow0[2 * p + 1] : ow1[2 * p - 3];
        acc = fmaf(rf.x, owa, fmaf(rf.y, owb, acc));
    }
    return acc;
}

// TWO sorted vi-segments per wave. WIDE-GATHER layout: 8 lanes x dwordx4
// per feature row -> one VMEM instruction covers 8 edges (R6: confirmed
// win; outstanding-cacheline capacity is the binding constraint).
__global__ __launch_bounds__(256, 3) void edge_kernel(
        const float* __restrict__ natt, const int* __restrict__ edges,
        const float* __restrict__ ey, const unsigned short* __restrict__ hc,
        const unsigned short* __restrict__ hu, const unsigned short* __restrict__ relt,
        const unsigned short* __restrict__ wsh, const unsigned short* __restrict__ fbh,
        const float* __restrict__ outw, float* __restrict__ out, int N) {
    int lane = threadIdx.x & 63;
    int g8 = lane >> 3, sub8 = lane & 7;
    int wid = blockIdx.x * 4 + (threadIdx.x >> 6);
    long baseA = (long)(wid * 2) * KPER;
    long baseB = baseA + KPER;
    const int* ebA = edges + baseA * 8;
    const int* ebB = edges + baseB * 8;

    // ---- metadata: per pass t, group g8 handles edge t*8+g8 (clamped) ----
    int2 h0A = *(const int2*)ebA;                 // (eg, vi)
    int2 h0B = *(const int2*)ebB;
    int2 m23A[3], m67A[3], m23B[3], m67B[3];      // (vj,rel), (e2vi,e2vj)
    #pragma unroll
    for (int t = 0; t < 3; ++t) {
        int e = t * 8 + g8; e = (e < KPER) ? e : (KPER - 1);
        m23A[t] = *(const int2*)(ebA + e * 8 + 2);
        m67A[t] = *(const int2*)(ebA + e * 8 + 6);
        m23B[t] = *(const int2*)(ebB + e * 8 + 2);
        m67B[t] = *(const int2*)(ebB + e * 8 + 6);
    }
    // atomic-tail operands, off the critical path
    int myvjA = 0, myvjB = 0; float eyA = 0.f, eyB = 0.f;
    if (lane < KPER) {
        myvjA = ebA[lane * 8 + 2];
        myvjB = ebB[lane * 8 + 2];
        eyA = ey[baseA + lane];
        eyB = ey[baseB + lane];
    }
    int egA = __builtin_amdgcn_readfirstlane(h0A.x);
    int viA = __builtin_amdgcn_readfirstlane(h0A.y);
    int egB = __builtin_amdgcn_readfirstlane(h0B.x);
    int viB = __builtin_amdgcn_readfirstlane(h0B.y);

    // ---- wide gathers: 4 per pass per segment (uint4 = 16B/lane) ---------
    uint4 GA0[3], GA2[3], GA3[3], GA4[3];
    #pragma unroll
    for (int t = 0; t < 3; ++t) {
        GA0[t] = *(const uint4*)(hc   + (size_t)m67A[t].x * D + sub8 * 8);
        GA2[t] = *(const uint4*)(relt + (size_t)m23A[t].y * D + sub8 * 8);
        GA3[t] = *(const uint4*)(hc   + (size_t)m67A[t].y * D + sub8 * 8);
        GA4[t] = *(const uint4*)(hu   + (size_t)m23A[t].x * D + sub8 * 8);
    }
    uint4 F1A = *(const uint4*)(hu + (size_t)viA * D + sub8 * 8);
    uint4 GB0[3], GB2[3], GB3[3], GB4[3];
    #pragma unroll
    for (int t = 0; t < 3; ++t) {
        GB0[t] = *(const uint4*)(hc   + (size_t)m67B[t].x * D + sub8 * 8);
        GB2[t] = *(const uint4*)(relt + (size_t)m23B[t].y * D + sub8 * 8);
        GB3[t] = *(const uint4*)(hc   + (size_t)m67B[t].y * D + sub8 * 8);
        GB4[t] = *(const uint4*)(hu   + (size_t)m23B[t].x * D + sub8 * 8);
    }
    uint4 F1B = *(const uint4*)(hu + (size_t)viB * D + sub8 * 8);
    float naA = natt[(size_t)egA * N + viA];
    float naB = natt[(size_t)egB * N + viB];

    // ---- per-lane constants (f16 ws/fb; f32 out_w), 8 features/lane ------
    uint4 wk4[8];
    #pragma unroll
    for (int k = 0; k < 8; ++k) wk4[k] = *(const uint4*)(wsh + k * D + sub8 * 8);
    uint4 fb4 = *(const uint4*)(fbh + sub8 * 8);
    floatx4 ow0 = *(const floatx4*)(outw + sub8 * 8);
    floatx4 ow1 = *(const floatx4*)(outw + sub8 * 8 + 4);
    __half2 z2 = __float2half2_rn(0.f);

    // ---- segment A: 3 passes x 8 edges, row8 reduce, softmax, scatter ----
    float mylA = -INFINITY, mylB = -INFINITY;
    #pragma unroll
    for (int t = 0; t < 3; ++t) {
        float acc = edge_acc8(GA0[t], GA2[t], GA3[t], GA4[t], F1A, wk4, fb4, ow0, ow1, z2);
        float rs = row8_sum(acc);                       // sums at lanes 8g+7
        float tot = __shfl(rs, ((lane & 7) << 3) + 7);  // edge lane = lane
        mylA = ((lane >> 3) == t && lane < KPER) ? tot : mylA;
    }
    float mxA = wave_max_b(mylA);
    float exA = __expf(mylA - mxA);
    float denA = wave_sum_b(exA);
    if (lane < KPER) {
        float tv = (exA / denA) * naA * eyA;
        atomicAdd(out + (size_t)egA * N + myvjA, tv);
    }
    // ---- segment B -------------------------------------------------------
    #pragma unroll
    for (int t = 0; t < 3; ++t) {
        float acc = edge_acc8(GB0[t], GB2[t], GB3[t], GB4[t], F1B, wk4, fb4, ow0, ow1, z2);
        float rs = row8_sum(acc);
        float tot = __shfl(rs, ((lane & 7) << 3) + 7);
        mylB = ((lane >> 3) == t && lane < KPER) ? tot : mylB;
    }
    float mxB = wave_max_b(mylB);
    float exB = __expf(mylB - mxB);
    float denB = wave_sum_b(exB);
    if (lane < KPER) {
        float tv = (exB / denB) * naB * eyB;
        atomicAdd(out + (size_t)egB * N + myvjB, tv);
    }
}

extern "C" void kernel_launch(void* const* d_in, const int* in_sizes, int n_in,
                              void* d_out, int out_size, void* d_ws, size_t ws_size,
                              hipStream_t stream) {
    const float* natt = (const float*)d_in[0];
    const int*   edges = (const int*)d_in[1];
    const float* ey   = (const float*)d_in[2];
    const float* hun  = (const float*)d_in[3];
    const float* hcon = (const float*)d_in[4];
    const float* Wc   = (const float*)d_in[5];
    const float* bc   = (const float*)d_in[6];
    const float* Wu   = (const float*)d_in[7];
    const float* bu   = (const float*)d_in[8];
    const float* relt = (const float*)d_in[9];
    const float* wsm  = (const float*)d_in[10];
    const float* fb   = (const float*)d_in[11];
    const float* outw = (const float*)d_in[12];
    float* out = (float*)d_out;

    int E    = in_sizes[2];          // 400000 edges
    int S    = E / KPER;             // 20000 sorted vi segments
    int nmem = in_sizes[4] / D;      // 131072 hidden_con rows
    int N    = in_sizes[3] / 256;    // 50000 nodes
    int nrel = in_sizes[9];          // 500*64

    int t64  = nmem / 16;            // 8192 row-tiles
    int t256 = N / 16;               // 3125 row-tiles
    int g64  = t64 / 8;              // 1024 blocks: 4 waves x 2 tiles each
    int g256b = (2 * t256 + 3) / 4;  // 1563 blocks: 1 (rt, half) task/wave

    unsigned short* hc  = (unsigned short*)d_ws;
    unsigned short* hu  = hc + (size_t)nmem * D;
    unsigned short* rb  = hu + (size_t)N * D;
    unsigned short* Wcp = rb + nrel;
    unsigned short* Wup = Wcp + 4096;
    unsigned short* wsh = Wup + 16384;
    unsigned short* fbh = wsh + 8 * D;

    prep<<<64, 256, 0, stream>>>(Wc, Wu, relt, wsm, fb, Wcp, Wup, rb, wsh, fbh,
                                 out, out_size, nrel);
    proj_fused<<<g256b + g64, 256, 0, stream>>>(hcon, Wcp, bc, hun, Wup, bu,
                                                hc, hu, t256, g256b);
    edge_kernel<<<S / 8, 256, 0, stream>>>(natt, edges, ey, hc, hu, rb,
                                           wsh, fbh, outw, out, N);
}

// Round 9
// 190.105 us; speedup vs baseline: 1.0375x; 1.0375x over previous
//
#include <hip/hip_runtime.h>
#include <hip/hip_bf16.h>
#include <hip/hip_fp16.h>

#define D 64
#define KPER 20

typedef __attribute__((ext_vector_type(8))) short short8;
typedef __attribute__((ext_vector_type(4))) float floatx4;

__device__ __forceinline__ unsigned short f2bfu(float x) {
    __hip_bfloat16 h = __float2bfloat16(x);
    return *reinterpret_cast<unsigned short*>(&h);
}
// f16 bits (tables are f16: 3 more mantissa bits than bf16 AND enables v_pk_* math)
__device__ __forceinline__ unsigned short f2hu(float x) {
    __half h = __float2half(x);
    return *reinterpret_cast<unsigned short*>(&h);
}
union UH2 { unsigned u; __half2 h; };
__device__ __forceinline__ __half2 u2h2(unsigned u) { UH2 x; x.u = u; return x.h; }
__device__ __forceinline__ unsigned pick4(uint4 v, int p) {
    return p == 0 ? v.x : p == 1 ? v.y : p == 2 ? v.z : v.w;   // p is compile-time under unroll
}

// HW packed f32->bf16 convert (RNE): src0 -> bits[15:0], src1 -> bits[31:16]
__device__ __forceinline__ unsigned cvt2bf(float lo, float hi) {
    unsigned r;
    asm("v_cvt_pk_bf16_f32 %0, %1, %2" : "=v"(r) : "v"(lo), "v"(hi));
    return r;
}

// guaranteed-available packed f16 max (avoid header-version-dependent __hmax2)
__device__ __forceinline__ __half2 pk_max(__half2 a, __half2 b) {
    __half2 r;
    asm("v_pk_max_f16 %0, %1, %2" : "=v"(r) : "v"(a), "v"(b));
    return r;
}

__device__ __forceinline__ float fast_tanh(float x) {
    float xc = fminf(fmaxf(x, -15.f), 15.f);
    float e = __expf(2.f * xc);
    return 1.f - 2.f * __builtin_amdgcn_rcpf(1.f + e);
}

// ---- DPP reductions (VALU pipe) ----------------------------------------
template<int CTRL>
__device__ __forceinline__ float dpp_add(float x) {
    int t = __builtin_amdgcn_update_dpp(0, __float_as_int(x), CTRL, 0xf, 0xf, true);
    return x + __int_as_float(t);
}
template<int CTRL>
__device__ __forceinline__ float dpp_max(float x) {
    int xi = __float_as_int(x);
    int t = __builtin_amdgcn_update_dpp(xi, xi, CTRL, 0xf, 0xf, false);
    return fmaxf(x, __int_as_float(t));
}
__device__ __forceinline__ float wave_sum_b(float x) {
    x = dpp_add<0x111>(x); x = dpp_add<0x112>(x);
    x = dpp_add<0x114>(x); x = dpp_add<0x118>(x);
    x = dpp_add<0x142>(x); x = dpp_add<0x143>(x);
    return __int_as_float(__builtin_amdgcn_readlane(__float_as_int(x), 63));
}
__device__ __forceinline__ float wave_max_b(float x) {
    x = dpp_max<0x111>(x); x = dpp_max<0x112>(x);
    x = dpp_max<0x114>(x); x = dpp_max<0x118>(x);
    x = dpp_max<0x142>(x); x = dpp_max<0x143>(x);
    return __int_as_float(__builtin_amdgcn_readlane(__float_as_int(x), 63));
}
// sum over each 8-lane subgroup; results at lanes 7/15 of each DPP row.
__device__ __forceinline__ float row8_sum(float x) {
    x = dpp_add<0x111>(x); x = dpp_add<0x112>(x);
    x = dpp_add<0x114>(x);
    return x;
}

// ---- prep: repack W into fragment-major bf16, convert rel/ws/fb to f16,
// zero out. ---------------------------------------------------------------
__global__ __launch_bounds__(256) void prep(
        const float* __restrict__ Wc, const float* __restrict__ Wu,
        const float* __restrict__ relf, const float* __restrict__ wsf,
        const float* __restrict__ fbf,
        unsigned short* __restrict__ Wcp, unsigned short* __restrict__ Wup,
        unsigned short* __restrict__ relb, unsigned short* __restrict__ wsh,
        unsigned short* __restrict__ fbh, float* __restrict__ outz,
        int nout, int nrel) {
    int tid = blockIdx.x * 256 + threadIdx.x;
    int nth = gridDim.x * 256;
    for (int i = tid; i < 4 * 2 * 64 * 8; i += nth) {
        int j = i & 7, lane = (i >> 3) & 63, f = i >> 9;
        int ct = f >> 1, kt = f & 1;
        int m = lane & 15, quad = lane >> 4;
        Wcp[i] = f2bfu(Wc[(kt * 32 + quad * 8 + j) * 64 + ct * 16 + m]);
    }
    for (int i = tid; i < 4 * 8 * 64 * 8; i += nth) {
        int j = i & 7, lane = (i >> 3) & 63, f = i >> 9;
        int ct = f >> 3, kt = f & 7;
        int m = lane & 15, quad = lane >> 4;
        Wup[i] = f2bfu(Wu[(kt * 32 + quad * 8 + j) * 64 + ct * 16 + m]);
    }
    for (int i = tid; i < nrel; i += nth) relb[i] = f2hu(relf[i]);
    for (int i = tid; i < 8 * D; i += nth) wsh[i] = f2hu(wsf[i]);
    for (int i = tid; i < D; i += nth) fbh[i] = f2hu(fbf[i]);
    for (int i = tid; i < nout; i += nth) outz[i] = 0.0f;
}

// ---- K=64 projection, pair of row-tiles per wave; packed-W frag init ---
__device__ __forceinline__ void proj64_pair(const float* __restrict__ h,
        const unsigned short* __restrict__ Wp, const float* __restrict__ b,
        unsigned short* __restrict__ out, int rt0) {
    constexpr int K = 64, KT = 2, CTN = 4;
    int lane = threadIdx.x & 63;
    int m = lane & 15, quad = lane >> 4;
    short8 bfr[CTN][KT];
    #pragma unroll
    for (int ct = 0; ct < CTN; ++ct)
        #pragma unroll
        for (int kt = 0; kt < KT; ++kt)
            bfr[ct][kt] = *(const short8*)(Wp + (((ct * 2 + kt) * 64 + lane) << 3));
    float bv[CTN];
    #pragma unroll
    for (int ct = 0; ct < CTN; ++ct) bv[ct] = b[ct * 16 + m];
    int rt1 = rt0 + 1;
    const float* hrow0 = h + (size_t)(rt0 * 16 + m) * K + quad * 8;
    const float* hrow1 = h + (size_t)(rt1 * 16 + m) * K + quad * 8;
    floatx4 a0[KT][2], a1[KT][2];
    #pragma unroll
    for (int kt = 0; kt < KT; ++kt) {
        a0[kt][0] = *(const floatx4*)(hrow0 + kt * 32);
        a0[kt][1] = *(const floatx4*)(hrow0 + kt * 32 + 4);
        a1[kt][0] = *(const floatx4*)(hrow1 + kt * 32);
        a1[kt][1] = *(const floatx4*)(hrow1 + kt * 32 + 4);
    }
    #pragma unroll
    for (int t = 0; t < 2; ++t) {
        floatx4 (*ar)[2] = t ? a1 : a0;
        int rt = t ? rt1 : rt0;
        floatx4 acc[CTN];
        #pragma unroll
        for (int ct = 0; ct < CTN; ++ct) acc[ct] = floatx4{0.f, 0.f, 0.f, 0.f};
        #pragma unroll
        for (int kt = 0; kt < KT; ++kt) {
            union { uint4 u; short8 s; } cc;
            cc.u.x = cvt2bf(ar[kt][0][0], ar[kt][0][1]);
            cc.u.y = cvt2bf(ar[kt][0][2], ar[kt][0][3]);
            cc.u.z = cvt2bf(ar[kt][1][0], ar[kt][1][1]);
            cc.u.w = cvt2bf(ar[kt][1][2], ar[kt][1][3]);
            short8 af = cc.s;
            #pragma unroll
            for (int ct = 0; ct < CTN; ++ct)
                acc[ct] = __builtin_amdgcn_mfma_f32_16x16x32_bf16(af, bfr[ct][kt], acc[ct], 0, 0, 0);
        }
        #pragma unroll
        for (int ct = 0; ct < CTN; ++ct) {
            int col = ct * 16 + m;
            #pragma unroll
            for (int reg = 0; reg < 4; ++reg) {
                int row = rt * 16 + quad * 4 + reg;
                out[(size_t)row * 64 + col] = f2hu(fast_tanh(acc[ct][reg] + bv[ct]));
            }
        }
    }
}

// ---- K=256 projection: ONE (rt, ct-half) task per wave; W fragments
// come from LDS (staged once per block). This removes the 64-VGPR bfr
// array (R7/R8: VGPR 80 -> Occupancy ~24% -> too few waves to hide the
// h-row HBM latency). ds_read_b128 is conflict-free (lane i reads 16B
// at byte offset i*16 within each 1KB fragment panel). -------------------
__device__ __forceinline__ void proj256_one(const float* __restrict__ h,
        const unsigned short* Wlds, const float* __restrict__ b,
        unsigned short* __restrict__ out, int ct0, int rt) {
    constexpr int K = 256, KT = 8, CTN = 2;
    int lane = threadIdx.x & 63;
    int m = lane & 15, quad = lane >> 4;
    float bv[CTN];
    #pragma unroll
    for (int ct = 0; ct < CTN; ++ct) bv[ct] = b[(ct0 + ct) * 16 + m];
    floatx4 acc[CTN];
    #pragma unroll
    for (int ct = 0; ct < CTN; ++ct) acc[ct] = floatx4{0.f, 0.f, 0.f, 0.f};
    const float* hrow = h + (size_t)(rt * 16 + m) * K + quad * 8;
    #pragma unroll
    for (int kt = 0; kt < KT; ++kt) {
        floatx4 v0 = *(const floatx4*)(hrow + kt * 32);
        floatx4 v1 = *(const floatx4*)(hrow + kt * 32 + 4);
        short8 b0 = *(const short8*)(Wlds + ((((ct0 + 0) * 8 + kt) * 64 + lane) << 3));
        short8 b1 = *(const short8*)(Wlds + ((((ct0 + 1) * 8 + kt) * 64 + lane) << 3));
        union { uint4 u; short8 s; } cc;
        cc.u.x = cvt2bf(v0[0], v0[1]);
        cc.u.y = cvt2bf(v0[2], v0[3]);
        cc.u.z = cvt2bf(v1[0], v1[1]);
        cc.u.w = cvt2bf(v1[2], v1[3]);
        short8 af = cc.s;
        acc[0] = __builtin_amdgcn_mfma_f32_16x16x32_bf16(af, b0, acc[0], 0, 0, 0);
        acc[1] = __builtin_amdgcn_mfma_f32_16x16x32_bf16(af, b1, acc[1], 0, 0, 0);
    }
    #pragma unroll
    for (int ct = 0; ct < CTN; ++ct) {
        int col = (ct0 + ct) * 16 + m;
        #pragma unroll
        for (int reg = 0; reg < 4; ++reg) {
            int row = rt * 16 + quad * 4 + reg;
            out[(size_t)row * 64 + col] = f2hu(fast_tanh(acc[ct][reg] + bv[ct]));
        }
    }
}

// Fused proj: proj256 single-task waves FIRST (bulk of work, W in LDS),
// then proj64 (register W fragments, 8KB L2-hot).
__global__ __launch_bounds__(256) void proj_fused(
        const float* __restrict__ hcon, const unsigned short* __restrict__ Wcp,
        const float* __restrict__ bc,
        const float* __restrict__ hun, const unsigned short* __restrict__ Wup,
        const float* __restrict__ bu,
        unsigned short* __restrict__ hc, unsigned short* __restrict__ hu,
        int t256, int g256b) {
    __shared__ __align__(16) unsigned short Wlds[16384];   // full packed Wup, 32KB
    int bid = blockIdx.x;
    int w = threadIdx.x >> 6;
    if (bid < g256b) {
        const uint4* src = (const uint4*)Wup;
        uint4* dst = (uint4*)Wlds;
        #pragma unroll
        for (int i = 0; i < 8; ++i)
            dst[threadIdx.x + i * 256] = src[threadIdx.x + i * 256];
        __syncthreads();
        int task = bid * 4 + w;
        if (task < 2 * t256)
            proj256_one(hun, Wlds, bu, hu, (task & 1) * 2, task >> 1);
    } else {
        int wid = (bid - g256b) * 4 + w;
        proj64_pair(hcon, Wcp, bc, hc, wid * 2);
    }
}

// Packed-f16 F-layer for ONE edge; each lane owns 8 features (4 __half2),
// gathered as ONE dwordx4 per feature table (8 lanes x 16B = full 128B row).
__device__ __forceinline__ float edge_acc8(
        uint4 G0, uint4 G2, uint4 G3, uint4 G4, uint4 F1,
        const uint4* __restrict__ wk4, uint4 fb4,
        floatx4 ow0, floatx4 ow1, __half2 z2) {
    float acc = 0.f;
    #pragma unroll
    for (int p = 0; p < 4; ++p) {
        __half2 F0 = u2h2(pick4(G0, p));
        __half2 F2 = u2h2(pick4(G2, p));
        __half2 F3 = u2h2(pick4(G3, p));
        __half2 F4 = u2h2(pick4(G4, p));
        __half2 f1 = u2h2(pick4(F1, p));
        __half2 fb2 = u2h2(pick4(fb4, p));
        __half2 w0 = u2h2(pick4(wk4[0], p));
        __half2 w1 = u2h2(pick4(wk4[1], p));
        __half2 w2 = u2h2(pick4(wk4[2], p));
        __half2 w3 = u2h2(pick4(wk4[3], p));
        __half2 w4 = u2h2(pick4(wk4[4], p));
        __half2 w5 = u2h2(pick4(wk4[5], p));
        __half2 w6 = u2h2(pick4(wk4[6], p));
        __half2 w7 = u2h2(pick4(wk4[7], p));
        __half2 t1 = __hfma2(F2, w1, w0);
        __half2 t2 = __hfma2(F2, w5, w4);
        __half2 t3 = __hfma2(F2, w3, w2);
        __half2 t4 = __hfma2(F2, w7, w6);
        __half2 uu = __hfma2(F0, t1, __hmul2(f1, t2));
        __half2 vv = __hfma2(F0, t3, __hmul2(f1, t4));
        __half2 od = __hfma2(F3, uu, __hfma2(F4, vv, fb2));
        __half2 r  = pk_max(od, z2);
        float2 rf  = __half22float2(r);
        float owa = (p < 2) ? ow0[2 * p]     : ow1[2 * p - 4];
        float owb = (p < 2) ? ow0[2 * p + 1] : ow1[2 * p - 3];
        acc = fmaf(rf.x, owa, fmaf(rf.y, owb, acc));
    }
    return acc;
}

// TWO sorted vi-segments per wave. WIDE-GATHER layout: 8 lanes x dwordx4
// per feature row -> one VMEM instruction covers 8 edges (R6: confirmed
// win; outstanding-cacheline capacity is the binding constraint).
__global__ __launch_bounds__(256, 3) void edge_kernel(
        const float* __restrict__ natt, const int* __restrict__ edges,
        const float* __restrict__ ey, const unsigned short* __restrict__ hc,
        const unsigned short* __restrict__ hu, const unsigned short* __restrict__ relt,
        const unsigned short* __restrict__ wsh, const unsigned short* __restrict__ fbh,
        const float* __restrict__ outw, float* __restrict__ out, int N) {
    int lane = threadIdx.x & 63;
    int g8 = lane >> 3, sub8 = lane & 7;
    int wid = blockIdx.x * 4 + (threadIdx.x >> 6);
    long baseA = (long)(wid * 2) * KPER;
    long baseB = baseA + KPER;
    const int* ebA = edges + baseA * 8;
    const int* ebB = edges + baseB * 8;

    // ---- metadata: per pass t, group g8 handles edge t*8+g8 (clamped) ----
    int2 h0A = *(const int2*)ebA;                 // (eg, vi)
    int2 h0B = *(const int2*)ebB;
    int2 m23A[3], m67A[3], m23B[3], m67B[3];      // (vj,rel), (e2vi,e2vj)
    #pragma unroll
    for (int t = 0; t < 3; ++t) {
        int e = t * 8 + g8; e = (e < KPER) ? e : (KPER - 1);
        m23A[t] = *(const int2*)(ebA + e * 8 + 2);
        m67A[t] = *(const int2*)(ebA + e * 8 + 6);
        m23B[t] = *(const int2*)(ebB + e * 8 + 2);
        m67B[t] = *(const int2*)(ebB + e * 8 + 6);
    }
    // atomic-tail operands, off the critical path
    int myvjA = 0, myvjB = 0; float eyA = 0.f, eyB = 0.f;
    if (lane < KPER) {
        myvjA = ebA[lane * 8 + 2];
        myvjB = ebB[lane * 8 + 2];
        eyA = ey[baseA + lane];
        eyB = ey[baseB + lane];
    }
    int egA = __builtin_amdgcn_readfirstlane(h0A.x);
    int viA = __builtin_amdgcn_readfirstlane(h0A.y);
    int egB = __builtin_amdgcn_readfirstlane(h0B.x);
    int viB = __builtin_amdgcn_readfirstlane(h0B.y);

    // ---- wide gathers: 4 per pass per segment (uint4 = 16B/lane) ---------
    uint4 GA0[3], GA2[3], GA3[3], GA4[3];
    #pragma unroll
    for (int t = 0; t < 3; ++t) {
        GA0[t] = *(const uint4*)(hc   + (size_t)m67A[t].x * D + sub8 * 8);
        GA2[t] = *(const uint4*)(relt + (size_t)m23A[t].y * D + sub8 * 8);
        GA3[t] = *(const uint4*)(hc   + (size_t)m67A[t].y * D + sub8 * 8);
        GA4[t] = *(const uint4*)(hu   + (size_t)m23A[t].x * D + sub8 * 8);
    }
    uint4 F1A = *(const uint4*)(hu + (size_t)viA * D + sub8 * 8);
    uint4 GB0[3], GB2[3], GB3[3], GB4[3];
    #pragma unroll
    for (int t = 0; t < 3; ++t) {
        GB0[t] = *(const uint4*)(hc   + (size_t)m67B[t].x * D + sub8 * 8);
        GB2[t] = *(const uint4*)(relt + (size_t)m23B[t].y * D + sub8 * 8);
        GB3[t] = *(const uint4*)(hc   + (size_t)m67B[t].y * D + sub8 * 8);
        GB4[t] = *(const uint4*)(hu   + (size_t)m23B[t].x * D + sub8 * 8);
    }
    uint4 F1B = *(const uint4*)(hu + (size_t)viB * D + sub8 * 8);
    float naA = natt[(size_t)egA * N + viA];
    float naB = natt[(size_t)egB * N + viB];

    // ---- per-lane constants (f16 ws/fb; f32 out_w), 8 features/lane ------
    uint4 wk4[8];
    #pragma unroll
    for (int k = 0; k < 8; ++k) wk4[k] = *(const uint4*)(wsh + k * D + sub8 * 8);
    uint4 fb4 = *(const uint4*)(fbh + sub8 * 8);
    floatx4 ow0 = *(const floatx4*)(outw + sub8 * 8);
    floatx4 ow1 = *(const floatx4*)(outw + sub8 * 8 + 4);
    __half2 z2 = __float2half2_rn(0.f);

    // ---- segment A: 3 passes x 8 edges, row8 reduce, softmax, scatter ----
    float mylA = -INFINITY, mylB = -INFINITY;
    #pragma unroll
    for (int t = 0; t < 3; ++t) {
        float acc = edge_acc8(GA0[t], GA2[t], GA3[t], GA4[t], F1A, wk4, fb4, ow0, ow1, z2);
        float rs = row8_sum(acc);                       // sums at lanes 8g+7
        float tot = __shfl(rs, ((lane & 7) << 3) + 7);  // edge lane = lane
        mylA = ((lane >> 3) == t && lane < KPER) ? tot : mylA;
    }
    float mxA = wave_max_b(mylA);
    float exA = __expf(mylA - mxA);
    float denA = wave_sum_b(exA);
    if (lane < KPER) {
        float tv = (exA / denA) * naA * eyA;
        atomicAdd(out + (size_t)egA * N + myvjA, tv);
    }
    // ---- segment B -------------------------------------------------------
    #pragma unroll
    for (int t = 0; t < 3; ++t) {
        float acc = edge_acc8(GB0[t], GB2[t], GB3[t], GB4[t], F1B, wk4, fb4, ow0, ow1, z2);
        float rs = row8_sum(acc);
        float tot = __shfl(rs, ((lane & 7) << 3) + 7);
        mylB = ((lane >> 3) == t && lane < KPER) ? tot : mylB;
    }
    float mxB = wave_max_b(mylB);
    float exB = __expf(mylB - mxB);
    float denB = wave_sum_b(exB);
    if (lane < KPER) {
        float tv = (exB / denB) * naB * eyB;
        atomicAdd(out + (size_t)egB * N + myvjB, tv);
    }
}

extern "C" void kernel_launch(void* const* d_in, const int* in_sizes, int n_in,
                              void* d_out, int out_size, void* d_ws, size_t ws_size,
                              hipStream_t stream) {
    const float* natt = (const float*)d_in[0];
    const int*   edges = (const int*)d_in[1];
    const float* ey   = (const float*)d_in[2];
    const float* hun  = (const float*)d_in[3];
    const float* hcon = (const float*)d_in[4];
    const float* Wc   = (const float*)d_in[5];
    const float* bc   = (const float*)d_in[6];
    const float* Wu   = (const float*)d_in[7];
    const float* bu   = (const float*)d_in[8];
    const float* relt = (const float*)d_in[9];
    const float* wsm  = (const float*)d_in[10];
    const float* fb   = (const float*)d_in[11];
    const float* outw = (const float*)d_in[12];
    float* out = (float*)d_out;

    int E    = in_sizes[2];          // 400000 edges
    int S    = E / KPER;             // 20000 sorted vi segments
    int nmem = in_sizes[4] / D;      // 131072 hidden_con rows
    int N    = in_sizes[3] / 256;    // 50000 nodes
    int nrel = in_sizes[9];          // 500*64

    int t64  = nmem / 16;            // 8192 row-tiles
    int t256 = N / 16;               // 3125 row-tiles
    int g64  = t64 / 8;              // 1024 blocks: 4 waves x 2 tiles each
    int g256b = (2 * t256 + 3) / 4;  // 1563 blocks: 1 (rt, half) task/wave

    unsigned short* hc  = (unsigned short*)d_ws;
    unsigned short* hu  = hc + (size_t)nmem * D;
    unsigned short* rb  = hu + (size_t)N * D;
    unsigned short* Wcp = rb + nrel;
    unsigned short* Wup = Wcp + 4096;
    unsigned short* wsh = Wup + 16384;
    unsigned short* fbh = wsh + 8 * D;

    prep<<<64, 256, 0, stream>>>(Wc, Wu, relt, wsm, fb, Wcp, Wup, rb, wsh, fbh,
                                 out, out_size, nrel);
    proj_fused<<<g256b + g64, 256, 0, stream>>>(hcon, Wcp, bc, hun, Wup, bu,
                                                hc, hu, t256, g256b);
    edge_kernel<<<S / 8, 256, 0, stream>>>(natt, edges, ey, hc, hu, rb,
                                           wsh, fbh, outw, out, N);
}